// Round 7
// baseline (108.425 us; speedup 1.0000x reference)
//
#include <hip/hip_runtime.h>
#include <hip/hip_bf16.h>

// out[b,m,d,f] = sum_{a,c} x[b,m,a,f] * y[b,m,c,f] * cgc[a,d,c]
// MFMA per bm: out[16,128] = W[16,256] . P[256,128], k=a*16+c,
//   W[d,k]=cgc[a,d,c] (register A-frags, layout verified R3-R6, absmax 0.25)
//   P[k,f]=x[a,f]*y[c,f] packed to bf16 on the fly.
//
// Round 7 vs round 6 (__syncthreads == s_waitcnt vmcnt(0): barrier drained the
// prefetch it was supposed to protect -> pipelining was a no-op):
//  - NO barriers. Each wave stages only the 32-col window it alone reads into
//    wave-private LDS (2-deep ring, 2x4KB/wave, 32KB/block, 4 blocks/CU).
//  - sync = this wave's own `s_waitcnt vmcnt(N)` (inline asm, FIFO semantics):
//    at iter i the younger ops are stores(i-1)[8] + stage(i+1)[4] -> vmcnt(12)
//    proves stage(i) retired while stage(i+1) stays in flight.
//  - 16 independent wave pipelines per CU -> loads flow continuously.

typedef __attribute__((ext_vector_type(8))) short  short8;
typedef __attribute__((ext_vector_type(4))) float  floatx4;
typedef __attribute__((ext_vector_type(4))) unsigned int uintx4;

#define AA 16
#define FF 128
#define NBM 4   // bm per block (one per wave-iteration)

static __device__ __forceinline__ unsigned int pack_bf16_2(float lo, float hi) {
    __hip_bfloat162 h = __float22bfloat162_rn(make_float2(lo, hi));  // v_cvt_pk_bf16_f32
    unsigned int u;
    __builtin_memcpy(&u, &h, 4);
    return u;
}

static __device__ __forceinline__ void gload_lds16(const float* g, float* l) {
    __builtin_amdgcn_global_load_lds(
        (const __attribute__((address_space(1))) void*)g,
        (__attribute__((address_space(3))) void*)l,
        16, 0, 0);
}

__global__ __launch_bounds__(256, 4)
void tpc_mfma_nobar_kernel(const float* __restrict__ x,
                           const float* __restrict__ y,
                           const float* __restrict__ cgc,
                           float* __restrict__ out) {
    // wave-private: [wave][buf][ x[16][32] | y[16][32] ]  = 4KB per buf
    __shared__ float lds[4 * 2 * 1024];

    const int tid  = threadIdx.x;
    const int w    = tid >> 6;         // wave 0..3 -> col window w*32
    const int lane = tid & 63;
    const int L    = lane & 15;        // A: m(=d); B: n(=f in tile); D: col
    const int quad = lane >> 4;
    const int qh   = quad >> 1;        // a parity
    const int c0   = (quad & 1) * 8;   // c sub-range

    const int bm0 = blockIdx.x * NBM;
    const size_t stride = (size_t)(AA * FF);

    float* wl = lds + w * 2048;                       // this wave's 8KB
    // staging: instr k covers rows 8k..8k+7 of the 32-col window
    //   global: row (k*8 + lane/8), col w*32 + (lane%8)*4   (16B/lane, coalesced)
    //   lds:    base + k*256 floats, lane-contig (lane0 offset 0 -> HW base)
    const int g_l   = (lane >> 3) * FF + w * 32 + (lane & 7) * 4;
    const int l_l   = lane * 4;

#define STAGE(bmi, buf)                                                        \
    {                                                                          \
        const float* xb_ = x + (size_t)(bmi) * stride;                         \
        const float* yb_ = y + (size_t)(bmi) * stride;                         \
        float* lb_ = wl + (buf) * 1024;                                        \
        gload_lds16(xb_ + g_l,          lb_ + l_l);                            \
        gload_lds16(xb_ + 8 * FF + g_l, lb_ + 256 + l_l);                      \
        gload_lds16(yb_ + g_l,          lb_ + 512 + l_l);                      \
        gload_lds16(yb_ + 8 * FF + g_l, lb_ + 768 + l_l);                      \
    }

    // ---- prologue: stage(0); wfrag build overlaps; stage(1) ----
    STAGE(bm0, 0);

    short8 wfrag[8];
#pragma unroll
    for (int t = 0; t < 8; ++t) {
        const float* wp = cgc + (2 * t + qh) * (AA * AA) + L * AA + c0;
        const floatx4 w0 = *(const floatx4*)(wp);
        const floatx4 w1 = *(const floatx4*)(wp + 4);
        uintx4 u;
        u.x = pack_bf16_2(w0.x, w0.y);
        u.y = pack_bf16_2(w0.z, w0.w);
        u.z = pack_bf16_2(w1.x, w1.y);
        u.w = pack_bf16_2(w1.z, w1.w);
        wfrag[t] = __builtin_bit_cast(short8, u);
    }

    STAGE(bm0 + 1, 1);

#pragma unroll
    for (int i = 0; i < NBM; ++i) {
        // wait for stage(i): younger VMEM = stores(i-1)[8] + stage(i+1)[4] (if issued)
        if (i + 1 < NBM) {
            asm volatile("s_waitcnt vmcnt(12)" ::: "memory");
        } else {
            asm volatile("s_waitcnt vmcnt(8)" ::: "memory");
        }

        const float* lb = wl + (i & 1) * 1024;   // x at 0, y at 512; rows of 32

        float xvA[8], xvB[8], yvA[8], yvB[8];
#pragma unroll
        for (int j = 0; j < 8; ++j) {
            yvA[j] = lb[512 + (c0 + j) * 32 + L];
            yvB[j] = lb[512 + (c0 + j) * 32 + L + 16];
        }
#pragma unroll
        for (int t = 0; t < 8; ++t) {
            xvA[t] = lb[(2 * t + qh) * 32 + L];
            xvB[t] = lb[(2 * t + qh) * 32 + L + 16];
        }

        floatx4 acc0 = {0.f, 0.f, 0.f, 0.f};
        floatx4 acc1 = {0.f, 0.f, 0.f, 0.f};
#pragma unroll
        for (int t = 0; t < 8; ++t) {
            uintx4 u;
            float xs = xvA[t];
            u.x = pack_bf16_2(xs * yvA[0], xs * yvA[1]);
            u.y = pack_bf16_2(xs * yvA[2], xs * yvA[3]);
            u.z = pack_bf16_2(xs * yvA[4], xs * yvA[5]);
            u.w = pack_bf16_2(xs * yvA[6], xs * yvA[7]);
            acc0 = __builtin_amdgcn_mfma_f32_16x16x32_bf16(
                       wfrag[t], __builtin_bit_cast(short8, u), acc0, 0, 0, 0);

            xs = xvB[t];
            u.x = pack_bf16_2(xs * yvB[0], xs * yvB[1]);
            u.y = pack_bf16_2(xs * yvB[2], xs * yvB[3]);
            u.z = pack_bf16_2(xs * yvB[4], xs * yvB[5]);
            u.w = pack_bf16_2(xs * yvB[6], xs * yvB[7]);
            acc1 = __builtin_amdgcn_mfma_f32_16x16x32_bf16(
                       wfrag[t], __builtin_bit_cast(short8, u), acc1, 0, 0, 0);
        }

        // stores: both 64B halves of this wave's 128B line per row
        float* ob = out + (size_t)(bm0 + i) * stride;
        const int fg = w * 32 + L;
#pragma unroll
        for (int r = 0; r < 4; ++r) {
            const int row = (quad * 4 + r) * FF;
            ob[row + fg]      = acc0[r];
            ob[row + fg + 16] = acc1[r];
        }

        // refill the buffer we just finished reading (ds_read data already
        // consumed into VGPRs -> safe to overwrite; no barrier needed)
        if (i + 2 < NBM)
            STAGE(bm0 + i + 2, i & 1);
    }
#undef STAGE
}

extern "C" void kernel_launch(void* const* d_in, const int* in_sizes, int n_in,
                              void* d_out, int out_size, void* d_ws, size_t ws_size,
                              hipStream_t stream) {
    const float* x   = (const float*)d_in[0];
    const float* y   = (const float*)d_in[1];
    const float* cgc = (const float*)d_in[2];
    float* out = (float*)d_out;

    // 4096 bm / 4 per block = 1024 blocks x 256 threads, 4 blocks/CU resident
    hipLaunchKernelGGL(tpc_mfma_nobar_kernel, dim3(1024), dim3(256), 0, stream,
                       x, y, cgc, out);
}